// Round 12
// baseline (219.602 us; speedup 1.0000x reference)
//
#include <hip/hip_runtime.h>
#include <hip/hip_bf16.h>
#include <math.h>

#define NN 50000
#define NE 800000
#define CAP 48              // per-dst edge capacity (max degree ~35 at 12 sigma)
#define NEG_SLOPE 0.2f
#define LOG2E 1.44269504088896340736f
#define EPB 4096            // edges per partition block
#define NPB 196             // partition blocks = ceil(NE/EPB)
#define NGB 3125            // GEMM blocks = NN/16
#define NCB 49              // coarse buckets (dst>>10), 1024 dsts each
#define CCAP 17408          // coarse bucket capacity (mean 16384 + 8 sigma)
#define QPB 4               // pass-2 window blocks per coarse bucket (256 dsts)

typedef __attribute__((ext_vector_type(8))) short bf16x8;
typedef __attribute__((ext_vector_type(4))) float f32x4;
typedef __attribute__((ext_vector_type(2))) float f32x2;

// ---- workspace layout (f32-word offsets), peak ~11.6M words = 46.4 MB ------
//  [0]                  flag
//  [100000, 100064)     gcnt u32 NCB coarse-bucket counters
//  [110000, 111689)     prm f32 param block (see k_setup_wprep)
//  [120000, 2520000)    sedge u32 NN*48 {ea_bf16_hi16 | src_u16}, bucketed
//  [2520000, 2570000)   deg u32 NN (dense, written by part2, <=CAP)
//  [3400000, 6600000)   xl1b bf16 N*128
//  [6600000, 9800000)   xr1b bf16 N*128 (b1r + b1e folded in)
//  [9800000, 9816384)   bfrag bf16 32768
//  [9900000, 11605984)  coarse uint2 NCB*CCAP {ea|src, dst}  (part1->part2)
//    ALIASED (used strictly earlier than):
//  [9900000, 10100000)  xl2b bf16 N*8 (16B rows, cols 0..4 used, +b2l)
//  [10300000, 10700000) xr2 f32 N*8 (stride 8, includes +b2r+b2e)
//
// prm layout (f32 @ +110000): canonical channel-indexed arrays
//  [0,128) we1f | [128,256) at1f*LOG2E | [256,384) bi1f | [384,1024) w2lt
//  [1024,1664) w2rt | [1664,1669) b2l | [1669,1674) b2r+b2e | [1674,1679) we2f
//  [1679,1684) at2f*LOG2E | [1684,1689) bi2f
// ----------------------------------------------------------------------------

__device__ __forceinline__ float ldf(const void* p, long i, int isbf) {
    if (isbf) {
        unsigned short raw = ((const unsigned short*)p)[i];
        return __uint_as_float(((unsigned)raw) << 16);
    }
    return ((const float*)p)[i];
}

__device__ __forceinline__ short f2bs(float f) {
    __hip_bfloat16 h = __float2bfloat16(f);
    short s; __builtin_memcpy(&s, &h, 2); return s;
}
__device__ __forceinline__ unsigned short f2bu(float f) {
    __hip_bfloat16 h = __float2bfloat16(f);
    unsigned short s; __builtin_memcpy(&s, &h, 2); return s;
}

// Sum within each 16-lane group: 4 DPP (VALU-pipe) adds. Verified constants.
__device__ __forceinline__ float red16(float p) {
    p += __int_as_float(__builtin_amdgcn_update_dpp(
             0, __float_as_int(p), 0xB1, 0xF, 0xF, false));
    p += __int_as_float(__builtin_amdgcn_update_dpp(
             0, __float_as_int(p), 0x4E, 0xF, 0xF, false));
    p += __int_as_float(__builtin_amdgcn_update_dpp(
             0, __float_as_int(p), 0x141, 0xF, 0xF, false));
    p += __int_as_float(__builtin_amdgcn_update_dpp(
             0, __float_as_int(p), 0x140, 0xF, 0xF, false));
    return p;
}

__device__ __forceinline__ float bperm(int addr4, float v) {
    return __int_as_float(__builtin_amdgcn_ds_bpermute(addr4, __float_as_int(v)));
}

// Blocks [0,128): pre-swizzle W = [W1l|W1r] into MFMA B-fragment order.
// Block 128: dtype flag + prm param fold + gcnt zero.
__global__ void k_setup_wprep(const void* x, int* flag, unsigned* gcnt,
                              const void* __restrict__ Wl,
                              const void* __restrict__ Wr,
                              unsigned short* __restrict__ bfrag,
                              const void* __restrict__ W1e,
                              const void* __restrict__ att1,
                              const void* __restrict__ bias1,
                              const void* __restrict__ W2l,
                              const void* __restrict__ b2l,
                              const void* __restrict__ W2r,
                              const void* __restrict__ b2r,
                              const void* __restrict__ b2e,
                              const void* __restrict__ W2e,
                              const void* __restrict__ att2,
                              const void* __restrict__ bias2,
                              float* __restrict__ prm) {
    // local per-wave dtype sniff (flag not yet visible in this kernel)
    unsigned short raw0 = ((const unsigned short*)x)[(threadIdx.x & 63) * 2];
    float v0 = __uint_as_float(((unsigned)raw0) << 16);
    bool sane = isfinite(v0) && fabsf(v0) > 1e-5f && fabsf(v0) < 1e3f;
    const int isbf = (__popcll(__ballot(sane)) > 32) ? 1 : 0;
    if (blockIdx.x == 128) {
        const int t = threadIdx.x;
        if (t == 0) *flag = isbf;
        if (t >= 192 && t < 192 + NCB) gcnt[t - 192] = 0u;
        if (t < 128) {
            prm[t]       = ldf(W1e, t, isbf);
            prm[128 + t] = ldf(att1, t, isbf) * LOG2E;
            prm[256 + t] = ldf(bias1, t, isbf);
#pragma unroll
            for (int c = 0; c < 5; c++) {
                prm[384 + c * 128 + t]  = ldf(W2l, (long)t * 5 + c, isbf);
                prm[1024 + c * 128 + t] = ldf(W2r, (long)t * 5 + c, isbf);
            }
        } else if (t < 133) {
            const int c = t - 128;
            prm[1664 + c] = ldf(b2l, c, isbf);
            prm[1669 + c] = ldf(b2r, c, isbf) + ldf(b2e, c, isbf);
            prm[1674 + c] = ldf(W2e, c, isbf);
            prm[1679 + c] = ldf(att2, c, isbf) * LOG2E;
            prm[1684 + c] = ldf(bias2, c, isbf);
        }
        return;
    }
    int idx = blockIdx.x * 256 + threadIdx.x;  // 0..32767
    int j = idx & 7, lane = (idx >> 3) & 63, ks = (idx >> 9) & 3, nt = idx >> 11;
    int k = ks * 32 + (lane >> 4) * 8 + j;
    int n = nt * 16 + (lane & 15);
    float v = (n < 128) ? ldf(Wl, (long)k * 128 + n, isbf)
                        : ldf(Wr, (long)k * 128 + (n - 128), isbf);
    bfrag[idx] = f2bu(v);
}

// Fused: blocks [0,NPB) coarse-partition edges (EPB=4096, 16/thread ->
// 9.6k device atomics, ~670B contiguous bucket runs); blocks [NPB,NPB+NGB)
// lin1 MFMA GEMM fills the rest of the machine from t=0.
__global__ __launch_bounds__(256) void k_part1_lin1(
    const void* __restrict__ x, const unsigned short* __restrict__ bfrag,
    const void* __restrict__ bl, const void* __restrict__ br,
    const void* __restrict__ be1,
    unsigned short* __restrict__ xl, unsigned short* __restrict__ xr,
    const int* __restrict__ ei, const void* __restrict__ ea,
    unsigned* __restrict__ gcnt, uint2* __restrict__ coarse,
    const int* __restrict__ flag) {
    const int isbf = flag[0];
    if (blockIdx.x < NPB) {
        __shared__ unsigned hist[64];
        __shared__ unsigned base[64];
        const int tid = threadIdx.x;
        if (tid < 64) hist[tid] = 0u;
        __syncthreads();
        const long e0 = (long)blockIdx.x * EPB + tid;
        int dv[16];
        unsigned pax[16], lr[16];
#pragma unroll
        for (int k = 0; k < 16; k++) {
            const long e = e0 + k * 256;
            if (e < NE) {
                dv[k] = ei[NE + e];
                pax[k] = (__float_as_uint(ldf(ea, e, isbf)) & 0xffff0000u)
                       | (unsigned)ei[e];
            } else dv[k] = -1;
        }
#pragma unroll
        for (int k = 0; k < 16; k++)
            if (dv[k] >= 0)
                lr[k] = atomicAdd(&hist[dv[k] >> 10], 1u);
        __syncthreads();
        if (tid < 64) {
            const unsigned h = hist[tid];
            base[tid] = h ? atomicAdd(&gcnt[tid], h) : 0u;   // device atomic
        }
        __syncthreads();
#pragma unroll
        for (int k = 0; k < 16; k++) {
            if (dv[k] >= 0) {
                const int cb = dv[k] >> 10;
                const unsigned p = base[cb] + lr[k];
                if (p < CCAP) {
                    uint2 pay;
                    pay.x = pax[k];
                    pay.y = (unsigned)dv[k];
                    coarse[(long)cb * CCAP + p] = pay;
                }
            }
        }
        return;
    }
    const int wave = threadIdx.x >> 6, lane = threadIdx.x & 63;
    const int mrow = lane & 15, quad = lane >> 4;
    const long mbase = (long)(blockIdx.x - NPB) * 16;
    bf16x8 afrag[4];
    if (isbf) {
        const unsigned short* xp = (const unsigned short*)x
                                 + (mbase + mrow) * 128 + quad * 8;
#pragma unroll
        for (int ks = 0; ks < 4; ks++)
            afrag[ks] = *(const bf16x8*)(xp + ks * 32);
    } else {
        const float* xp = (const float*)x + (mbase + mrow) * 128 + quad * 8;
#pragma unroll
        for (int ks = 0; ks < 4; ks++) {
            const float4 u0 = *(const float4*)(xp + ks * 32);
            const float4 u1 = *(const float4*)(xp + ks * 32 + 4);
            bf16x8 a;
            a[0] = f2bs(u0.x); a[1] = f2bs(u0.y); a[2] = f2bs(u0.z); a[3] = f2bs(u0.w);
            a[4] = f2bs(u1.x); a[5] = f2bs(u1.y); a[6] = f2bs(u1.z); a[7] = f2bs(u1.w);
            afrag[ks] = a;
        }
    }
#pragma unroll
    for (int q = 0; q < 4; q++) {
        const int nt = wave * 4 + q;
        f32x4 acc = {0.f, 0.f, 0.f, 0.f};
#pragma unroll
        for (int ks = 0; ks < 4; ks++) {
            const bf16x8 bfr = *(const bf16x8*)(bfrag + ((nt * 4 + ks) * 64 + lane) * 8);
            acc = __builtin_amdgcn_mfma_f32_16x16x32_bf16(afrag[ks], bfr, acc, 0, 0, 0);
        }
        const int ng = nt * 16 + (lane & 15);
        const float bv = (ng < 128)
            ? ldf(bl, ng, isbf)
            : ldf(br, ng - 128, isbf) + ldf(be1, ng - 128, isbf);
        unsigned short* dst = (ng < 128) ? xl : xr;
        const int col = ng & 127;
#pragma unroll
        for (int reg = 0; reg < 4; reg++) {
            const long row = mbase + quad * 4 + reg;
            dst[row * 128 + col] = f2bu(acc[reg] + bv);
        }
    }
}

// Pass 2: fine bucketing with LDS atomics only (zero device atomics).
__global__ __launch_bounds__(256) void k_part2(
    const uint2* __restrict__ coarse, const unsigned* __restrict__ gcnt,
    unsigned* __restrict__ sedge, unsigned* __restrict__ deg) {
    const int cb = blockIdx.x >> 2, q = blockIdx.x & 3;
    const int d0 = cb * 1024 + q * 256;
    __shared__ unsigned lcnt[256];
    const int tid = threadIdx.x;
    lcnt[tid] = 0u;
    __syncthreads();
    const int m = min((int)gcnt[cb], CCAP);
    const uint2* __restrict__ cbp = coarse + (long)cb * CCAP;
    for (int i = tid; i < m; i += 256) {
        const uint2 pay = cbp[i];
        const int ld = (int)pay.y - d0;
        if ((unsigned)ld < 256u) {
            const unsigned pos = atomicAdd(&lcnt[ld], 1u);
            if (pos < CAP)
                sedge[(long)pay.y * CAP + pos] = pay.x;
        }
    }
    __syncthreads();
    const int d = d0 + tid;
    if (d < NN) deg[d] = min(lcnt[tid], (unsigned)CAP);
}

// R11/R12 attn1 pass: 2 edges per wave (lanes 0-31 = edge A, 32-63 = edge B),
// 4 ch/lane. Head = 16-lane group -> logit reduce is pure-DPP red16; tree'd
// dot (depth 3). One 8B gather per lane serves 2 edges (256B/edge, coalesced).
__device__ __forceinline__ void pass2e(unsigned ga, unsigned gb,
                                       const unsigned* __restrict__ xl,
                                       int wofs, bool hi,
                                       const float* we4, const float* xr4,
                                       const float* at4,
                                       float& lsum, float* acc) {
    const int sA = (int)(ga & 0xffffu);
    const int sB = (int)(gb & 0xffffu);
    const float eA = __uint_as_float(ga & 0xffff0000u);
    const float eB = __uint_as_float(gb & 0xffff0000u);
    const int s = hi ? sB : sA;
    const float ee = hi ? eB : eA;
    const uint2 u = *(const uint2*)(xl + ((long)s << 6) + wofs);
    float xv[4];
    xv[0] = __uint_as_float(u.x << 16);
    xv[1] = __uint_as_float(u.x & 0xffff0000u);
    xv[2] = __uint_as_float(u.y << 16);
    xv[3] = __uint_as_float(u.y & 0xffff0000u);
    float t[4];
#pragma unroll
    for (int j = 0; j < 4; j++) {
        t[j] = fmaf(ee, we4[j], xr4[j]) + xv[j];
        t[j] = fmaxf(t[j], t[j] * NEG_SLOPE);
    }
    float f0 = t[0] * at4[0];
    float f1 = t[2] * at4[2];
    f0 = fmaf(t[1], at4[1], f0);
    f1 = fmaf(t[3], at4[3], f1);
    float p = red16(f0 + f1);              // per-head logit (16-lane group)
    p = fminf(fmaxf(p, -60.f), 60.f);
    const float w = __builtin_amdgcn_exp2f(p);
    lsum += w;
#pragma unroll
    for (int j = 0; j < 4; j++) acc[j] = fmaf(w, xv[j], acc[j]);
}

// Fused layer-1 attention + bias+ELU + layer-2 linears.
// R12: FOUR independent pair-chains (8 edges in flight) — each edge's
// compute is a ~100-cycle serial chain (unpack->fma->leaky->dot->red16->
// clamp->exp2->acc); R11's 2 chains couldn't cover that latency (measured
// 138 cy/edge vs ~55 static). Tails: pair loop, then masked single.
__global__ __launch_bounds__(256) void k_attn1(
    const unsigned* __restrict__ deg, const unsigned* __restrict__ sedge,
    const unsigned* __restrict__ xl, const unsigned* __restrict__ xr,
    const float* __restrict__ prm,
    unsigned short* __restrict__ xl2b, float* __restrict__ xr2) {
    const int n = __builtin_amdgcn_readfirstlane(
        blockIdx.x * 4 + (threadIdx.x >> 6));
    if (n >= NN) return;
    const int lane = threadIdx.x & 63;
    const int hl = lane & 31;
    const bool hi = lane >= 32;
    const int cL = ((hl >> 4) << 6) | ((hl & 15) << 2);  // channel base (x4)
    const int wofs = cL >> 1;                            // u32-word offset
    // per-lane constants: 4 channels of xr row (has b1r+b1e), We, att*LOG2E
    const uint2 xru = *(const uint2*)(xr + (long)n * 64 + wofs);
    float xr4[4], we4[4], at4[4];
    xr4[0] = __uint_as_float(xru.x << 16);
    xr4[1] = __uint_as_float(xru.x & 0xffff0000u);
    xr4[2] = __uint_as_float(xru.y << 16);
    xr4[3] = __uint_as_float(xru.y & 0xffff0000u);
    {
        const float4 wef = *(const float4*)(prm + cL);
        const float4 atf = *(const float4*)(prm + 128 + cL);
        we4[0] = wef.x; we4[1] = wef.y; we4[2] = wef.z; we4[3] = wef.w;
        at4[0] = atf.x; at4[1] = atf.y; at4[2] = atf.z; at4[3] = atf.w;
    }
    float lsA = 0.f, lsB = 0.f, lsC = 0.f, lsD = 0.f;
    float aA[4] = {0.f, 0.f, 0.f, 0.f};
    float aB[4] = {0.f, 0.f, 0.f, 0.f};
    float aC[4] = {0.f, 0.f, 0.f, 0.f};
    float aD[4] = {0.f, 0.f, 0.f, 0.f};
    const int dg = (int)__builtin_amdgcn_readfirstlane(deg[n]);
    const long base = (long)n * CAP;
    const uint4* __restrict__ sld = (const uint4*)(sedge + base);
    int g = 0;
    for (; g + 8 <= dg; g += 8) {          // 8 edges, 4 independent chains
        const uint4 e0 = sld[g >> 2];      // uniform -> s_load_dwordx4
        const uint4 e1 = sld[(g >> 2) + 1];
        pass2e(e0.x, e0.y, xl, wofs, hi, we4, xr4, at4, lsA, aA);
        pass2e(e0.z, e0.w, xl, wofs, hi, we4, xr4, at4, lsB, aB);
        pass2e(e1.x, e1.y, xl, wofs, hi, we4, xr4, at4, lsC, aC);
        pass2e(e1.z, e1.w, xl, wofs, hi, we4, xr4, at4, lsD, aD);
    }
    for (; g + 2 <= dg; g += 2)            // pair tail (<=3 pairs)
        pass2e(sedge[base + g], sedge[base + g + 1],
               xl, wofs, hi, we4, xr4, at4, lsA, aA);
    if (g < dg) {                          // single tail: hi half -> w=0
        const unsigned ga = sedge[base + g];
        const int s0 = (int)(ga & 0xffffu);
        const float e0 = __uint_as_float(ga & 0xffff0000u);
        const uint2 u = *(const uint2*)(xl + ((long)s0 << 6) + wofs);
        float xv[4];
        xv[0] = __uint_as_float(u.x << 16);
        xv[1] = __uint_as_float(u.x & 0xffff0000u);
        xv[2] = __uint_as_float(u.y << 16);
        xv[3] = __uint_as_float(u.y & 0xffff0000u);
        float t[4];
#pragma unroll
        for (int j = 0; j < 4; j++) {
            t[j] = fmaf(e0, we4[j], xr4[j]) + xv[j];
            t[j] = fmaxf(t[j], t[j] * NEG_SLOPE);
        }
        float f0 = t[0] * at4[0];
        float f1 = t[2] * at4[2];
        f0 = fmaf(t[1], at4[1], f0);
        f1 = fmaf(t[3], at4[3], f1);
        float p = red16(f0 + f1);
        p = fminf(fmaxf(p, -60.f), 60.f);
        float w = __builtin_amdgcn_exp2f(p);
        w = hi ? 0.f : w;                  // only lanes 0-31 contribute
        lsB += w;
#pragma unroll
        for (int j = 0; j < 4; j++) aB[j] = fmaf(w, xv[j], aB[j]);
    }
    // combine the four chains, then the two wave halves (same channels)
    float lsum = (lsA + lsB) + (lsC + lsD);
    float acc[4];
#pragma unroll
    for (int j = 0; j < 4; j++) acc[j] = (aA[j] + aB[j]) + (aC[j] + aD[j]);
    lsum += __shfl_xor(lsum, 32);
#pragma unroll
    for (int j = 0; j < 4; j++) acc[j] += __shfl_xor(acc[j], 32);
    // transpose 4ch/lane (lanes 0-31) -> 2ch/lane (64 lanes): dest lane M
    // takes ch {2M,2M+1} = regs {2(M&1), +1} of src lane ((M>>5)<<4)+((M&31)>>1)
    const int ls = ((lane >> 5) << 4) + ((lane & 31) >> 1);
    const int a4 = ls << 2;
    const float b0 = bperm(a4, acc[0]), b1 = bperm(a4, acc[1]);
    const float b2 = bperm(a4, acc[2]), b3 = bperm(a4, acc[3]);
    const float lsr = bperm(a4, lsum);
    const bool odd = (lane & 1) != 0;
    const float av0 = odd ? b2 : b0;
    const float av1 = odd ? b3 : b1;
    const float inv = 1.f / fmaxf(lsr, 1e-20f);
    const float2 bsv = *(const float2*)(prm + 256 + 2 * lane);
    float h0 = fmaf(av0, inv, bsv.x);
    float h1 = fmaf(av1, inv, bsv.y);
    h0 = h0 > 0.f ? h0 : __builtin_amdgcn_exp2f(h0 * LOG2E) - 1.f;
    h1 = h1 > 0.f ? h1 : __builtin_amdgcn_exp2f(h1 * LOG2E) - 1.f;
    // fused layer-2 linears: 2x5 dots over 128 channels; transposed W2 rows
    // give coalesced dwordx2 loads; DPP steps then shfl.
    float pl[5], pr[5];
#pragma unroll
    for (int c = 0; c < 5; c++) {
        const float2 wl = *(const float2*)(prm + 384 + c * 128 + 2 * lane);
        const float2 wr = *(const float2*)(prm + 1024 + c * 128 + 2 * lane);
        pl[c] = h0 * wl.x + h1 * wl.y;
        pr[c] = h0 * wr.x + h1 * wr.y;
        pl[c] = red16(pl[c]);
        pr[c] = red16(pr[c]);
    }
#pragma unroll
    for (int off = 16; off <= 32; off <<= 1) {
#pragma unroll
        for (int c = 0; c < 5; c++) {
            pl[c] += __shfl_xor(pl[c], off);
            pr[c] += __shfl_xor(pr[c], off);
        }
    }
    if (lane == 0) {
        // xl2 row packed to bf16x8 (16B) -> single uint4 store
        uint4 pk;
        pk.x = (unsigned)f2bu(pl[0] + prm[1664])
             | ((unsigned)f2bu(pl[1] + prm[1665]) << 16);
        pk.y = (unsigned)f2bu(pl[2] + prm[1666])
             | ((unsigned)f2bu(pl[3] + prm[1667]) << 16);
        pk.z = (unsigned)f2bu(pl[4] + prm[1668]);
        pk.w = 0u;
        *(uint4*)(xl2b + (long)n * 8) = pk;
#pragma unroll
        for (int c = 0; c < 5; c++)
            xr2[(long)n * 8 + c] = pr[c] + prm[1669 + c];
    }
}

// Fused layer-2 attention: 16 lanes per dst node (4 nodes/wave), per-lane
// accumulation, DPP reduce per node; no-max softmax; bf16-packed xl2 gather.
__global__ __launch_bounds__(256) void k_attn2(
    const unsigned* __restrict__ deg, const unsigned* __restrict__ sedge,
    const unsigned short* __restrict__ xl2b, const float* __restrict__ xr2,
    const float* __restrict__ prm,
    void* __restrict__ out, const int* __restrict__ flag) {
    const int isbf = flag[0];
    const int n = blockIdx.x * 16 + (threadIdx.x >> 4);
    if (n >= NN) return;
    const int l16 = threadIdx.x & 15;
    f32x4 xrb4; float xrb4s;
    f32x4 wev4; float wev4s;
    f32x4 atv4; float atv4s;
    {
        const float4 r0 = *(const float4*)(xr2 + (long)n * 8);  // includes b2r+b2e
        xrb4 = (f32x4){r0.x, r0.y, r0.z, r0.w};
        xrb4s = xr2[(long)n * 8 + 4];
        wev4 = (f32x4){prm[1674], prm[1675], prm[1676], prm[1677]};
        wev4s = prm[1678];
        atv4 = (f32x4){prm[1679], prm[1680], prm[1681], prm[1682]};  // *LOG2E
        atv4s = prm[1683];
    }
    const f32x4 ns4 = {NEG_SLOPE, NEG_SLOPE, NEG_SLOPE, NEG_SLOPE};
    float lw = 0.f, laccs = 0.f;
    f32x4 lacc4 = {0.f, 0.f, 0.f, 0.f};
    const int dg = (int)deg[n];
    const long base = (long)n * CAP;
    for (int idx = l16; idx < dg; idx += 16) {
        const unsigned eg = sedge[base + idx];
        const int s = eg & 0xffffu;
        const float a = __uint_as_float(eg & 0xffff0000u);
        const uint4 u = *(const uint4*)(xl2b + (long)s * 8);   // one 16B gather
        f32x4 xls4;
        xls4.x = __uint_as_float(u.x << 16);
        xls4.y = __uint_as_float(u.x & 0xffff0000u);
        xls4.z = __uint_as_float(u.y << 16);
        xls4.w = __uint_as_float(u.y & 0xffff0000u);
        const float xlss = __uint_as_float(u.z << 16);
        f32x4 v4 = xls4 + __builtin_elementwise_fma((f32x4){a, a, a, a}, wev4, xrb4);
        v4 = __builtin_elementwise_max(v4, v4 * ns4);
        float vs = xlss + fmaf(a, wev4s, xrb4s);
        vs = fmaxf(vs, NEG_SLOPE * vs);
        const f32x4 pd = v4 * atv4;
        float p = ((pd.x + pd.y) + (pd.z + pd.w)) + vs * atv4s;
        p = fminf(fmaxf(p, -60.f), 60.f);
        const float w = __builtin_amdgcn_exp2f(p);
        lw += w;
        lacc4 = __builtin_elementwise_fma((f32x4){w, w, w, w}, xls4, lacc4);
        laccs = fmaf(w, xlss, laccs);
    }
    // per-node (16-lane group) reduce entirely on the DPP/VALU pipe
    lw = red16(lw);
    lacc4.x = red16(lacc4.x);
    lacc4.y = red16(lacc4.y);
    lacc4.z = red16(lacc4.z);
    lacc4.w = red16(lacc4.w);
    laccs = red16(laccs);
    if (l16 == 0) {
        const float inv = 1.f / fmaxf(lw, 1e-20f);
        float o[5] = {lacc4.x, lacc4.y, lacc4.z, lacc4.w, laccs};
#pragma unroll
        for (int c = 0; c < 5; c++) {
            const float v = fmaf(o[c], inv, prm[1684 + c]);
            if (isbf) ((__hip_bfloat16*)out)[(long)n * 5 + c] = __float2bfloat16(v);
            else      ((float*)out)[(long)n * 5 + c] = v;
        }
    }
}

extern "C" void kernel_launch(void* const* d_in, const int* in_sizes, int n_in,
                              void* d_out, int out_size, void* d_ws, size_t ws_size,
                              hipStream_t stream) {
    const void* x    = d_in[0];
    const int*  ei   = (const int*)d_in[1];
    const void* ea   = d_in[2];
    const void* W1l  = d_in[3];
    const void* b1l  = d_in[4];
    const void* W1r  = d_in[5];
    const void* b1r  = d_in[6];
    const void* W1e  = d_in[7];
    const void* b1e  = d_in[8];
    const void* att1 = d_in[9];
    const void* bias1= d_in[10];
    const void* W2l  = d_in[11];
    const void* b2l  = d_in[12];
    const void* W2r  = d_in[13];
    const void* b2r  = d_in[14];
    const void* W2e  = d_in[15];
    const void* b2e  = d_in[16];
    const void* att2 = d_in[17];
    const void* bias2= d_in[18];

    float* W = (float*)d_ws;
    int*            flag    = (int*)W;
    unsigned*       gcnt    = (unsigned*)(W + 100000);    // NCB coarse counters
    float*          prm     = W + 110000;                 // f32 param block
    unsigned*       sedge   = (unsigned*)(W + 120000);    // NN*CAP bucketed
    unsigned*       deg     = (unsigned*)(W + 2520000);   // dense u32 NN
    unsigned short* xl1b    = (unsigned short*)(W + 3400000);
    unsigned short* xr1b    = (unsigned short*)(W + 6600000);
    unsigned short* bfrag   = (unsigned short*)(W + 9800000);
    uint2*          coarse  = (uint2*)(W + 9900000);      // part1->part2 only
    unsigned short* xl2b    = (unsigned short*)(W + 9900000); // aliased (later)
    float*          xr2     = W + 10300000;                   // aliased (later)

    // W pre-swizzle + dtype flag + param fold + gcnt zero (one dispatch)
    k_setup_wprep<<<129, 256, 0, stream>>>(x, flag, gcnt, W1l, W1r, bfrag,
                                           W1e, att1, bias1,
                                           W2l, b2l, W2r, b2r, b2e,
                                           W2e, att2, bias2, prm);
    // coarse partition (EPB=4096, 9.6k device atomics) + lin1 MFMA fused
    k_part1_lin1<<<NPB + NGB, 256, 0, stream>>>(
        x, bfrag, b1l, b1r, b1e, xl1b, xr1b, ei, ea, gcnt, coarse, flag);
    // fine bucketing: LDS-atomic ranking into per-window sedge, dense deg
    k_part2<<<NCB * QPB, 256, 0, stream>>>(coarse, gcnt, sedge, deg);
    // Layer 1 (+ fused layer-2 linears)
    k_attn1<<<(NN + 3) / 4, 256, 0, stream>>>(deg, sedge,
                                              (const unsigned*)xl1b, (const unsigned*)xr1b,
                                              prm, xl2b, xr2);
    // Layer 2
    k_attn2<<<(NN * 16 + 255) / 256, 256, 0, stream>>>(deg, sedge, xl2b, xr2,
                                                       prm, d_out, flag);
}

// Round 14
// 211.540 us; speedup vs baseline: 1.0381x; 1.0381x over previous
//
#include <hip/hip_runtime.h>
#include <hip/hip_bf16.h>
#include <math.h>

#define NN 50000
#define NE 800000
#define CAP 48              // per-dst edge capacity (max degree ~35 at 12 sigma)
#define NEG_SLOPE 0.2f
#define LOG2E 1.44269504088896340736f
#define EPB 4096            // edges per partition block
#define NPB 196             // partition blocks = ceil(NE/EPB)
#define NGB 3125            // GEMM blocks = NN/16
#define NCB 49              // coarse buckets (dst>>10), 1024 dsts each
#define CCAP 17408          // coarse bucket capacity (mean 16384 + 8 sigma)
#define QPB 4               // pass-2 window blocks per coarse bucket (256 dsts)

typedef __attribute__((ext_vector_type(8))) short bf16x8;
typedef __attribute__((ext_vector_type(4))) float f32x4;
typedef __attribute__((ext_vector_type(2))) float f32x2;

// ---- workspace layout (f32-word offsets), peak ~11.6M words = 46.4 MB ------
//  [0]                  flag
//  [100000, 100064)     gcnt u32 NCB coarse-bucket counters
//  [110000, 111689)     prm f32 param block (see k_setup_wprep)
//  [120000, 2520000)    sedge u32 NN*48 {ea_bf16_hi16 | src_u16}, bucketed
//  [2520000, 2570000)   deg u32 NN (dense, written by part2, <=CAP)
//  [3400000, 6600000)   xl1b bf16 N*128
//  [6600000, 9800000)   xr1b bf16 N*128 (b1r + b1e folded in)
//  [9800000, 9816384)   bfrag bf16 32768
//  [9900000, 11605984)  coarse uint2 NCB*CCAP {ea|src, dst}  (part1->part2)
//    ALIASED (used strictly earlier than):
//  [9900000, 10100000)  xl2b bf16 N*8 (16B rows, cols 0..4 used, +b2l)
//  [10300000, 10700000) xr2 f32 N*8 (stride 8, includes +b2r+b2e)
//
// prm layout (f32 @ +110000): canonical channel-indexed arrays
//  [0,128) we1f | [128,256) at1f*LOG2E | [256,384) bi1f | [384,1024) w2lt
//  [1024,1664) w2rt | [1664,1669) b2l | [1669,1674) b2r+b2e | [1674,1679) we2f
//  [1679,1684) at2f*LOG2E | [1684,1689) bi2f
// ----------------------------------------------------------------------------

__device__ __forceinline__ float ldf(const void* p, long i, int isbf) {
    if (isbf) {
        unsigned short raw = ((const unsigned short*)p)[i];
        return __uint_as_float(((unsigned)raw) << 16);
    }
    return ((const float*)p)[i];
}

__device__ __forceinline__ short f2bs(float f) {
    __hip_bfloat16 h = __float2bfloat16(f);
    short s; __builtin_memcpy(&s, &h, 2); return s;
}
__device__ __forceinline__ unsigned short f2bu(float f) {
    __hip_bfloat16 h = __float2bfloat16(f);
    unsigned short s; __builtin_memcpy(&s, &h, 2); return s;
}

// Single-instruction clamp: v_med3_f32 (VOP3, assembles on gfx950).
__device__ __forceinline__ float med3(float a, float lo, float hi) {
    float d; asm("v_med3_f32 %0, %1, %2, %3" : "=v"(d) : "v"(a), "v"(lo), "v"(hi));
    return d;
}

// Sum within each 16-lane group: 4 DPP (VALU-pipe) adds. Verified constants.
__device__ __forceinline__ float red16(float p) {
    p += __int_as_float(__builtin_amdgcn_update_dpp(
             0, __float_as_int(p), 0xB1, 0xF, 0xF, false));
    p += __int_as_float(__builtin_amdgcn_update_dpp(
             0, __float_as_int(p), 0x4E, 0xF, 0xF, false));
    p += __int_as_float(__builtin_amdgcn_update_dpp(
             0, __float_as_int(p), 0x141, 0xF, 0xF, false));
    p += __int_as_float(__builtin_amdgcn_update_dpp(
             0, __float_as_int(p), 0x140, 0xF, 0xF, false));
    return p;
}

__device__ __forceinline__ float bperm(int addr4, float v) {
    return __int_as_float(__builtin_amdgcn_ds_bpermute(addr4, __float_as_int(v)));
}

// Blocks [0,128): pre-swizzle W = [W1l|W1r] into MFMA B-fragment order.
// Block 128: dtype flag + prm param fold + gcnt zero.
__global__ void k_setup_wprep(const void* x, int* flag, unsigned* gcnt,
                              const void* __restrict__ Wl,
                              const void* __restrict__ Wr,
                              unsigned short* __restrict__ bfrag,
                              const void* __restrict__ W1e,
                              const void* __restrict__ att1,
                              const void* __restrict__ bias1,
                              const void* __restrict__ W2l,
                              const void* __restrict__ b2l,
                              const void* __restrict__ W2r,
                              const void* __restrict__ b2r,
                              const void* __restrict__ b2e,
                              const void* __restrict__ W2e,
                              const void* __restrict__ att2,
                              const void* __restrict__ bias2,
                              float* __restrict__ prm) {
    // local per-wave dtype sniff (flag not yet visible in this kernel)
    unsigned short raw0 = ((const unsigned short*)x)[(threadIdx.x & 63) * 2];
    float v0 = __uint_as_float(((unsigned)raw0) << 16);
    bool sane = isfinite(v0) && fabsf(v0) > 1e-5f && fabsf(v0) < 1e3f;
    const int isbf = (__popcll(__ballot(sane)) > 32) ? 1 : 0;
    if (blockIdx.x == 128) {
        const int t = threadIdx.x;
        if (t == 0) *flag = isbf;
        if (t >= 192 && t < 192 + NCB) gcnt[t - 192] = 0u;
        if (t < 128) {
            prm[t]       = ldf(W1e, t, isbf);
            prm[128 + t] = ldf(att1, t, isbf) * LOG2E;
            prm[256 + t] = ldf(bias1, t, isbf);
#pragma unroll
            for (int c = 0; c < 5; c++) {
                prm[384 + c * 128 + t]  = ldf(W2l, (long)t * 5 + c, isbf);
                prm[1024 + c * 128 + t] = ldf(W2r, (long)t * 5 + c, isbf);
            }
        } else if (t < 133) {
            const int c = t - 128;
            prm[1664 + c] = ldf(b2l, c, isbf);
            prm[1669 + c] = ldf(b2r, c, isbf) + ldf(b2e, c, isbf);
            prm[1674 + c] = ldf(W2e, c, isbf);
            prm[1679 + c] = ldf(att2, c, isbf) * LOG2E;
            prm[1684 + c] = ldf(bias2, c, isbf);
        }
        return;
    }
    int idx = blockIdx.x * 256 + threadIdx.x;  // 0..32767
    int j = idx & 7, lane = (idx >> 3) & 63, ks = (idx >> 9) & 3, nt = idx >> 11;
    int k = ks * 32 + (lane >> 4) * 8 + j;
    int n = nt * 16 + (lane & 15);
    float v = (n < 128) ? ldf(Wl, (long)k * 128 + n, isbf)
                        : ldf(Wr, (long)k * 128 + (n - 128), isbf);
    bfrag[idx] = f2bu(v);
}

// Fused: blocks [0,NPB) coarse-partition edges (EPB=4096, 16/thread ->
// 9.6k device atomics, ~670B contiguous bucket runs); blocks [NPB,NPB+NGB)
// lin1 MFMA GEMM fills the rest of the machine from t=0.
__global__ __launch_bounds__(256) void k_part1_lin1(
    const void* __restrict__ x, const unsigned short* __restrict__ bfrag,
    const void* __restrict__ bl, const void* __restrict__ br,
    const void* __restrict__ be1,
    unsigned short* __restrict__ xl, unsigned short* __restrict__ xr,
    const int* __restrict__ ei, const void* __restrict__ ea,
    unsigned* __restrict__ gcnt, uint2* __restrict__ coarse,
    const int* __restrict__ flag) {
    const int isbf = flag[0];
    if (blockIdx.x < NPB) {
        __shared__ unsigned hist[64];
        __shared__ unsigned base[64];
        const int tid = threadIdx.x;
        if (tid < 64) hist[tid] = 0u;
        __syncthreads();
        const long e0 = (long)blockIdx.x * EPB + tid;
        int dv[16];
        unsigned pax[16], lr[16];
#pragma unroll
        for (int k = 0; k < 16; k++) {
            const long e = e0 + k * 256;
            if (e < NE) {
                dv[k] = ei[NE + e];
                pax[k] = (__float_as_uint(ldf(ea, e, isbf)) & 0xffff0000u)
                       | (unsigned)ei[e];
            } else dv[k] = -1;
        }
#pragma unroll
        for (int k = 0; k < 16; k++)
            if (dv[k] >= 0)
                lr[k] = atomicAdd(&hist[dv[k] >> 10], 1u);
        __syncthreads();
        if (tid < 64) {
            const unsigned h = hist[tid];
            base[tid] = h ? atomicAdd(&gcnt[tid], h) : 0u;   // device atomic
        }
        __syncthreads();
#pragma unroll
        for (int k = 0; k < 16; k++) {
            if (dv[k] >= 0) {
                const int cb = dv[k] >> 10;
                const unsigned p = base[cb] + lr[k];
                if (p < CCAP) {
                    uint2 pay;
                    pay.x = pax[k];
                    pay.y = (unsigned)dv[k];
                    coarse[(long)cb * CCAP + p] = pay;
                }
            }
        }
        return;
    }
    const int wave = threadIdx.x >> 6, lane = threadIdx.x & 63;
    const int mrow = lane & 15, quad = lane >> 4;
    const long mbase = (long)(blockIdx.x - NPB) * 16;
    bf16x8 afrag[4];
    if (isbf) {
        const unsigned short* xp = (const unsigned short*)x
                                 + (mbase + mrow) * 128 + quad * 8;
#pragma unroll
        for (int ks = 0; ks < 4; ks++)
            afrag[ks] = *(const bf16x8*)(xp + ks * 32);
    } else {
        const float* xp = (const float*)x + (mbase + mrow) * 128 + quad * 8;
#pragma unroll
        for (int ks = 0; ks < 4; ks++) {
            const float4 u0 = *(const float4*)(xp + ks * 32);
            const float4 u1 = *(const float4*)(xp + ks * 32 + 4);
            bf16x8 a;
            a[0] = f2bs(u0.x); a[1] = f2bs(u0.y); a[2] = f2bs(u0.z); a[3] = f2bs(u0.w);
            a[4] = f2bs(u1.x); a[5] = f2bs(u1.y); a[6] = f2bs(u1.z); a[7] = f2bs(u1.w);
            afrag[ks] = a;
        }
    }
#pragma unroll
    for (int q = 0; q < 4; q++) {
        const int nt = wave * 4 + q;
        f32x4 acc = {0.f, 0.f, 0.f, 0.f};
#pragma unroll
        for (int ks = 0; ks < 4; ks++) {
            const bf16x8 bfr = *(const bf16x8*)(bfrag + ((nt * 4 + ks) * 64 + lane) * 8);
            acc = __builtin_amdgcn_mfma_f32_16x16x32_bf16(afrag[ks], bfr, acc, 0, 0, 0);
        }
        const int ng = nt * 16 + (lane & 15);
        const float bv = (ng < 128)
            ? ldf(bl, ng, isbf)
            : ldf(br, ng - 128, isbf) + ldf(be1, ng - 128, isbf);
        unsigned short* dst = (ng < 128) ? xl : xr;
        const int col = ng & 127;
#pragma unroll
        for (int reg = 0; reg < 4; reg++) {
            const long row = mbase + quad * 4 + reg;
            dst[row * 128 + col] = f2bu(acc[reg] + bv);
        }
    }
}

// Pass 2: fine bucketing with LDS atomics only (zero device atomics).
__global__ __launch_bounds__(256) void k_part2(
    const uint2* __restrict__ coarse, const unsigned* __restrict__ gcnt,
    unsigned* __restrict__ sedge, unsigned* __restrict__ deg) {
    const int cb = blockIdx.x >> 2, q = blockIdx.x & 3;
    const int d0 = cb * 1024 + q * 256;
    __shared__ unsigned lcnt[256];
    const int tid = threadIdx.x;
    lcnt[tid] = 0u;
    __syncthreads();
    const int m = min((int)gcnt[cb], CCAP);
    const uint2* __restrict__ cbp = coarse + (long)cb * CCAP;
    for (int i = tid; i < m; i += 256) {
        const uint2 pay = cbp[i];
        const int ld = (int)pay.y - d0;
        if ((unsigned)ld < 256u) {
            const unsigned pos = atomicAdd(&lcnt[ld], 1u);
            if (pos < CAP)
                sedge[(long)pay.y * CAP + pos] = pay.x;
        }
    }
    __syncthreads();
    const int d = d0 + tid;
    if (d < NN) deg[d] = min(lcnt[tid], (unsigned)CAP);
}

// R13 attn1 pass (R11 shape, frozen): 2 edges per wave (lanes 0-31 = edge A,
// 32-63 = edge B), 4 ch/lane. Head = 16-lane group -> logit reduce is pure-DPP
// red16; tree'd dot (depth 3); med3 clamp. One 8B gather per lane serves 2
// edges (256B/edge, coalesced). 2 chains / 28 VGPR — R12's 4 chains dropped
// occupancy 64->43% and regressed; TLP beats ILP here.
__device__ __forceinline__ void pass2e(unsigned ga, unsigned gb,
                                       const unsigned* __restrict__ xl,
                                       int wofs, bool hi,
                                       const float* we4, const float* xr4,
                                       const float* at4,
                                       float& lsum, float* acc) {
    const int sA = (int)(ga & 0xffffu);
    const int sB = (int)(gb & 0xffffu);
    const float eA = __uint_as_float(ga & 0xffff0000u);
    const float eB = __uint_as_float(gb & 0xffff0000u);
    const int s = hi ? sB : sA;
    const float ee = hi ? eB : eA;
    const uint2 u = *(const uint2*)(xl + ((long)s << 6) + wofs);
    float xv[4];
    xv[0] = __uint_as_float(u.x << 16);
    xv[1] = __uint_as_float(u.x & 0xffff0000u);
    xv[2] = __uint_as_float(u.y << 16);
    xv[3] = __uint_as_float(u.y & 0xffff0000u);
    float t[4];
#pragma unroll
    for (int j = 0; j < 4; j++) {
        t[j] = fmaf(ee, we4[j], xr4[j]) + xv[j];
        t[j] = fmaxf(t[j], t[j] * NEG_SLOPE);
    }
    float f0 = t[0] * at4[0];
    float f1 = t[2] * at4[2];
    f0 = fmaf(t[1], at4[1], f0);
    f1 = fmaf(t[3], at4[3], f1);
    float p = red16(f0 + f1);              // per-head logit (16-lane group)
    p = med3(p, -60.f, 60.f);
    const float w = __builtin_amdgcn_exp2f(p);
    lsum += w;
#pragma unroll
    for (int j = 0; j < 4; j++) acc[j] = fmaf(w, xv[j], acc[j]);
}

// Fused layer-1 attention + bias+ELU + layer-2 linears.  (R11 structure)
__global__ __launch_bounds__(256) void k_attn1(
    const unsigned* __restrict__ deg, const unsigned* __restrict__ sedge,
    const unsigned* __restrict__ xl, const unsigned* __restrict__ xr,
    const float* __restrict__ prm,
    unsigned short* __restrict__ xl2b, float* __restrict__ xr2) {
    const int n = __builtin_amdgcn_readfirstlane(
        blockIdx.x * 4 + (threadIdx.x >> 6));
    if (n >= NN) return;
    const int lane = threadIdx.x & 63;
    const int hl = lane & 31;
    const bool hi = lane >= 32;
    const int cL = ((hl >> 4) << 6) | ((hl & 15) << 2);  // channel base (x4)
    const int wofs = cL >> 1;                            // u32-word offset
    // per-lane constants: 4 channels of xr row (has b1r+b1e), We, att*LOG2E
    const uint2 xru = *(const uint2*)(xr + (long)n * 64 + wofs);
    float xr4[4], we4[4], at4[4];
    xr4[0] = __uint_as_float(xru.x << 16);
    xr4[1] = __uint_as_float(xru.x & 0xffff0000u);
    xr4[2] = __uint_as_float(xru.y << 16);
    xr4[3] = __uint_as_float(xru.y & 0xffff0000u);
    {
        const float4 wef = *(const float4*)(prm + cL);
        const float4 atf = *(const float4*)(prm + 128 + cL);
        we4[0] = wef.x; we4[1] = wef.y; we4[2] = wef.z; we4[3] = wef.w;
        at4[0] = atf.x; at4[1] = atf.y; at4[2] = atf.z; at4[3] = atf.w;
    }
    float lsumA = 0.f, lsumB = 0.f;
    float accA[4] = {0.f, 0.f, 0.f, 0.f};
    float accB[4] = {0.f, 0.f, 0.f, 0.f};
    const int dg = (int)__builtin_amdgcn_readfirstlane(deg[n]);
    const long base = (long)n * CAP;
    const uint4* __restrict__ sld = (const uint4*)(sedge + base);
    const int dg4 = dg & ~3;
    int g = 0;
    if (dg4 > 0) {
        uint4 eg4 = sld[0];                      // uniform -> s_load_dwordx4
        for (g = 0; g < dg4; g += 4) {
            uint4 nxt = eg4;
            if (g + 4 < dg4) nxt = sld[(g >> 2) + 1];   // prefetch next group
            pass2e(eg4.x, eg4.y, xl, wofs, hi, we4, xr4, at4, lsumA, accA);
            pass2e(eg4.z, eg4.w, xl, wofs, hi, we4, xr4, at4, lsumB, accB);
            eg4 = nxt;
        }
    }
    if (g + 1 < dg) {                            // tail pair
        pass2e(sedge[base + g], sedge[base + g + 1],
               xl, wofs, hi, we4, xr4, at4, lsumA, accA);
        g += 2;
    }
    if (g < dg) {                                // tail single: hi half -> w=0
        const unsigned ga = sedge[base + g];
        const int s0 = (int)(ga & 0xffffu);
        const float e0 = __uint_as_float(ga & 0xffff0000u);
        const uint2 u = *(const uint2*)(xl + ((long)s0 << 6) + wofs);
        float xv[4];
        xv[0] = __uint_as_float(u.x << 16);
        xv[1] = __uint_as_float(u.x & 0xffff0000u);
        xv[2] = __uint_as_float(u.y << 16);
        xv[3] = __uint_as_float(u.y & 0xffff0000u);
        float t[4];
#pragma unroll
        for (int j = 0; j < 4; j++) {
            t[j] = fmaf(e0, we4[j], xr4[j]) + xv[j];
            t[j] = fmaxf(t[j], t[j] * NEG_SLOPE);
        }
        float f0 = t[0] * at4[0];
        float f1 = t[2] * at4[2];
        f0 = fmaf(t[1], at4[1], f0);
        f1 = fmaf(t[3], at4[3], f1);
        float p = red16(f0 + f1);
        p = med3(p, -60.f, 60.f);
        float w = __builtin_amdgcn_exp2f(p);
        w = hi ? 0.f : w;                        // only lanes 0-31 contribute
        lsumA += w;
#pragma unroll
        for (int j = 0; j < 4; j++) accA[j] = fmaf(w, xv[j], accA[j]);
    }
    // combine the two chains, then the two wave halves (same channels)
    float lsum = lsumA + lsumB;
    float acc[4];
#pragma unroll
    for (int j = 0; j < 4; j++) acc[j] = accA[j] + accB[j];
    lsum += __shfl_xor(lsum, 32);
#pragma unroll
    for (int j = 0; j < 4; j++) acc[j] += __shfl_xor(acc[j], 32);
    // transpose 4ch/lane (lanes 0-31) -> 2ch/lane (64 lanes): dest lane M
    // takes ch {2M,2M+1} = regs {2(M&1), +1} of src lane ((M>>5)<<4)+((M&31)>>1)
    const int ls = ((lane >> 5) << 4) + ((lane & 31) >> 1);
    const int a4 = ls << 2;
    const float b0 = bperm(a4, acc[0]), b1 = bperm(a4, acc[1]);
    const float b2 = bperm(a4, acc[2]), b3 = bperm(a4, acc[3]);
    const float lsr = bperm(a4, lsum);
    const bool odd = (lane & 1) != 0;
    const float av0 = odd ? b2 : b0;
    const float av1 = odd ? b3 : b1;
    const float inv = 1.f / fmaxf(lsr, 1e-20f);
    const float2 bsv = *(const float2*)(prm + 256 + 2 * lane);
    float h0 = fmaf(av0, inv, bsv.x);
    float h1 = fmaf(av1, inv, bsv.y);
    h0 = h0 > 0.f ? h0 : __builtin_amdgcn_exp2f(h0 * LOG2E) - 1.f;
    h1 = h1 > 0.f ? h1 : __builtin_amdgcn_exp2f(h1 * LOG2E) - 1.f;
    // fused layer-2 linears: 2x5 dots over 128 channels; transposed W2 rows
    // give coalesced dwordx2 loads; DPP steps then shfl.
    float pl[5], pr[5];
#pragma unroll
    for (int c = 0; c < 5; c++) {
        const float2 wl = *(const float2*)(prm + 384 + c * 128 + 2 * lane);
        const float2 wr = *(const float2*)(prm + 1024 + c * 128 + 2 * lane);
        pl[c] = h0 * wl.x + h1 * wl.y;
        pr[c] = h0 * wr.x + h1 * wr.y;
        pl[c] = red16(pl[c]);
        pr[c] = red16(pr[c]);
    }
#pragma unroll
    for (int off = 16; off <= 32; off <<= 1) {
#pragma unroll
        for (int c = 0; c < 5; c++) {
            pl[c] += __shfl_xor(pl[c], off);
            pr[c] += __shfl_xor(pr[c], off);
        }
    }
    if (lane == 0) {
        // xl2 row packed to bf16x8 (16B) -> single uint4 store
        uint4 pk;
        pk.x = (unsigned)f2bu(pl[0] + prm[1664])
             | ((unsigned)f2bu(pl[1] + prm[1665]) << 16);
        pk.y = (unsigned)f2bu(pl[2] + prm[1666])
             | ((unsigned)f2bu(pl[3] + prm[1667]) << 16);
        pk.z = (unsigned)f2bu(pl[4] + prm[1668]);
        pk.w = 0u;
        *(uint4*)(xl2b + (long)n * 8) = pk;
#pragma unroll
        for (int c = 0; c < 5; c++)
            xr2[(long)n * 8 + c] = pr[c] + prm[1669 + c];
    }
}

// Fused layer-2 attention: 16 lanes per dst node (4 nodes/wave), per-lane
// accumulation, DPP reduce per node; no-max softmax; bf16-packed xl2 gather.
__global__ __launch_bounds__(256) void k_attn2(
    const unsigned* __restrict__ deg, const unsigned* __restrict__ sedge,
    const unsigned short* __restrict__ xl2b, const float* __restrict__ xr2,
    const float* __restrict__ prm,
    void* __restrict__ out, const int* __restrict__ flag) {
    const int isbf = flag[0];
    const int n = blockIdx.x * 16 + (threadIdx.x >> 4);
    if (n >= NN) return;
    const int l16 = threadIdx.x & 15;
    f32x4 xrb4; float xrb4s;
    f32x4 wev4; float wev4s;
    f32x4 atv4; float atv4s;
    {
        const float4 r0 = *(const float4*)(xr2 + (long)n * 8);  // includes b2r+b2e
        xrb4 = (f32x4){r0.x, r0.y, r0.z, r0.w};
        xrb4s = xr2[(long)n * 8 + 4];
        wev4 = (f32x4){prm[1674], prm[1675], prm[1676], prm[1677]};
        wev4s = prm[1678];
        atv4 = (f32x4){prm[1679], prm[1680], prm[1681], prm[1682]};  // *LOG2E
        atv4s = prm[1683];
    }
    const f32x4 ns4 = {NEG_SLOPE, NEG_SLOPE, NEG_SLOPE, NEG_SLOPE};
    float lw = 0.f, laccs = 0.f;
    f32x4 lacc4 = {0.f, 0.f, 0.f, 0.f};
    const int dg = (int)deg[n];
    const long base = (long)n * CAP;
    for (int idx = l16; idx < dg; idx += 16) {
        const unsigned eg = sedge[base + idx];
        const int s = eg & 0xffffu;
        const float a = __uint_as_float(eg & 0xffff0000u);
        const uint4 u = *(const uint4*)(xl2b + (long)s * 8);   // one 16B gather
        f32x4 xls4;
        xls4.x = __uint_as_float(u.x << 16);
        xls4.y = __uint_as_float(u.x & 0xffff0000u);
        xls4.z = __uint_as_float(u.y << 16);
        xls4.w = __uint_as_float(u.y & 0xffff0000u);
        const float xlss = __uint_as_float(u.z << 16);
        f32x4 v4 = xls4 + __builtin_elementwise_fma((f32x4){a, a, a, a}, wev4, xrb4);
        v4 = __builtin_elementwise_max(v4, v4 * ns4);
        float vs = xlss + fmaf(a, wev4s, xrb4s);
        vs = fmaxf(vs, NEG_SLOPE * vs);
        const f32x4 pd = v4 * atv4;
        float p = ((pd.x + pd.y) + (pd.z + pd.w)) + vs * atv4s;
        p = fminf(fmaxf(p, -60.f), 60.f);
        const float w = __builtin_amdgcn_exp2f(p);
        lw += w;
        lacc4 = __builtin_elementwise_fma((f32x4){w, w, w, w}, xls4, lacc4);
        laccs = fmaf(w, xlss, laccs);
    }
    // per-node (16-lane group) reduce entirely on the DPP/VALU pipe
    lw = red16(lw);
    lacc4.x = red16(lacc4.x);
    lacc4.y = red16(lacc4.y);
    lacc4.z = red16(lacc4.z);
    lacc4.w = red16(lacc4.w);
    laccs = red16(laccs);
    if (l16 == 0) {
        const float inv = 1.f / fmaxf(lw, 1e-20f);
        float o[5] = {lacc4.x, lacc4.y, lacc4.z, lacc4.w, laccs};
#pragma unroll
        for (int c = 0; c < 5; c++) {
            const float v = fmaf(o[c], inv, prm[1684 + c]);
            if (isbf) ((__hip_bfloat16*)out)[(long)n * 5 + c] = __float2bfloat16(v);
            else      ((float*)out)[(long)n * 5 + c] = v;
        }
    }
}

extern "C" void kernel_launch(void* const* d_in, const int* in_sizes, int n_in,
                              void* d_out, int out_size, void* d_ws, size_t ws_size,
                              hipStream_t stream) {
    const void* x    = d_in[0];
    const int*  ei   = (const int*)d_in[1];
    const void* ea   = d_in[2];
    const void* W1l  = d_in[3];
    const void* b1l  = d_in[4];
    const void* W1r  = d_in[5];
    const void* b1r  = d_in[6];
    const void* W1e  = d_in[7];
    const void* b1e  = d_in[8];
    const void* att1 = d_in[9];
    const void* bias1= d_in[10];
    const void* W2l  = d_in[11];
    const void* b2l  = d_in[12];
    const void* W2r  = d_in[13];
    const void* b2r  = d_in[14];
    const void* W2e  = d_in[15];
    const void* b2e  = d_in[16];
    const void* att2 = d_in[17];
    const void* bias2= d_in[18];

    float* W = (float*)d_ws;
    int*            flag    = (int*)W;
    unsigned*       gcnt    = (unsigned*)(W + 100000);    // NCB coarse counters
    float*          prm     = W + 110000;                 // f32 param block
    unsigned*       sedge   = (unsigned*)(W + 120000);    // NN*CAP bucketed
    unsigned*       deg     = (unsigned*)(W + 2520000);   // dense u32 NN
    unsigned short* xl1b    = (unsigned short*)(W + 3400000);
    unsigned short* xr1b    = (unsigned short*)(W + 6600000);
    unsigned short* bfrag   = (unsigned short*)(W + 9800000);
    uint2*          coarse  = (uint2*)(W + 9900000);      // part1->part2 only
    unsigned short* xl2b    = (unsigned short*)(W + 9900000); // aliased (later)
    float*          xr2     = W + 10300000;                   // aliased (later)

    // W pre-swizzle + dtype flag + param fold + gcnt zero (one dispatch)
    k_setup_wprep<<<129, 256, 0, stream>>>(x, flag, gcnt, W1l, W1r, bfrag,
                                           W1e, att1, bias1,
                                           W2l, b2l, W2r, b2r, b2e,
                                           W2e, att2, bias2, prm);
    // coarse partition (EPB=4096, 9.6k device atomics) + lin1 MFMA fused
    k_part1_lin1<<<NPB + NGB, 256, 0, stream>>>(
        x, bfrag, b1l, b1r, b1e, xl1b, xr1b, ei, ea, gcnt, coarse, flag);
    // fine bucketing: LDS-atomic ranking into per-window sedge, dense deg
    k_part2<<<NCB * QPB, 256, 0, stream>>>(coarse, gcnt, sedge, deg);
    // Layer 1 (+ fused layer-2 linears)
    k_attn1<<<(NN + 3) / 4, 256, 0, stream>>>(deg, sedge,
                                              (const unsigned*)xl1b, (const unsigned*)xr1b,
                                              prm, xl2b, xr2);
    // Layer 2
    k_attn2<<<(NN * 16 + 255) / 256, 256, 0, stream>>>(deg, sedge, xl2b, xr2,
                                                       prm, d_out, flag);
}